// Round 1
// baseline (784.375 us; speedup 1.0000x reference)
//
#include <hip/hip_runtime.h>

// WaveNet block: B=16, C=256, T=4096, LAYERS=8, K=2 (causal, dilation 2^l).
// Per layer: Y = Wk1 @ X + Wk0 @ X(shifted by -d)  for filter and gate,
// Zs = tanh(F)*sigmoid(G), Zout += Zs.
// Strategy: bf16 MFMA GEMM (M=256, N=B*T, K=512), m97-style 128x128 tile,
// BK=64, global_load_lds(16B) staging. X kept in [b][t][c] bf16 layout with a
// 128-wide zero pad on t (covers max dilation 128 -> no boundary branches).

typedef __attribute__((ext_vector_type(8))) short s16x8;
typedef __attribute__((ext_vector_type(4))) float f32x4;

#define NB 16
#define NC 256
#define NT 4096
#define TPAD 4224   // 128 (zero pad) + 4096
#define PADT 128
#define NLAYERS 8
#define KTOT 512    // C * Ktap

__device__ __forceinline__ short f2bf(float x) {
  union { float f; unsigned u; } v; v.f = x;
  unsigned u = v.u;
  unsigned r = (u + 0x7fffu + ((u >> 16) & 1u)) >> 16;  // RNE
  return (short)r;
}

__device__ __forceinline__ void async16(short* lp, const short* gp) {
  __builtin_amdgcn_global_load_lds(
      (const __attribute__((address_space(1))) unsigned int*)gp,
      (__attribute__((address_space(3))) unsigned int*)lp,
      16, 0, 0);
}

// ---------------- prep kernels ----------------

// zero the t<0 pad region of both ping-pong X buffers (ws is poisoned 0xAA)
__global__ void zero_pads(short* __restrict__ X0, short* __restrict__ X1) {
  int idx = blockIdx.x * 256 + threadIdx.x;     // over NB*PADT*NC = 524288
  if (idx >= NB * PADT * NC) return;
  int b = idx >> 15;                            // / (PADT*NC)
  int rem = idx & 32767;
  size_t off = (size_t)b * TPAD * NC + rem;
  X0[off] = 0;
  X1[off] = 0;
}

// ys [b][c][t] fp32  ->  X0 [b][128+t][c] bf16 (LDS-tiled transpose)
__global__ void transpose_cast(const float* __restrict__ ys, short* __restrict__ X0) {
  __shared__ float tile[64][65];
  const int b = blockIdx.z, c0 = blockIdx.y * 64, t0 = blockIdx.x * 64;
  const int tid = threadIdx.x;
#pragma unroll
  for (int i = 0; i < 16; ++i) {
    int c = (tid >> 6) + i * 4;
    int t = tid & 63;
    tile[c][t] = ys[((size_t)(b * NC + c0 + c)) * NT + t0 + t];
  }
  __syncthreads();
#pragma unroll
  for (int i = 0; i < 2; ++i) {
    int q = tid + i * 256;                      // 512 chunks of 8 bf16
    int t = q >> 3, cc = (q & 7) * 8;
    s16x8 v;
#pragma unroll
    for (int j = 0; j < 8; ++j) v[j] = f2bf(tile[cc + j][t]);
    *(s16x8*)&X0[((size_t)(b * TPAD + PADT + t0 + t)) * NC + c0 + cc] = v;
  }
}

// weights [l][co][ci][kw] fp32 -> [l][co][kw*256+ci] bf16, filter & gate
__global__ void convert_w(const float* __restrict__ fw, const float* __restrict__ gw,
                          short* __restrict__ Wf, short* __restrict__ Wg) {
  int idx = blockIdx.x * 256 + threadIdx.x;     // over 8*256*512 = 1048576
  if (idx >= NLAYERS * NC * KTOT) return;
  int k = idx & (KTOT - 1);
  int row = idx >> 9;                           // l*256+co
  int kw = k >> 8, ci = k & 255;
  int src = (row * NC + ci) * 2 + kw;
  Wf[idx] = f2bf(fw[src]);
  Wg[idx] = f2bf(gw[src]);
}

// ---------------- fused layer kernel ----------------
// grid (2, 32, 16): m-tile, t-tile, batch.  256 threads = 4 waves.
// flags: bit0 = first layer (Zout store, not rmw); bit1 = last (skip Zs out)
__global__ __launch_bounds__(256, 2)
void wavenet_layer(const short* __restrict__ Xin, short* __restrict__ Xout,
                   const short* __restrict__ Wf, const short* __restrict__ Wg,
                   const float* __restrict__ bia_f, const float* __restrict__ bia_g,
                   float* __restrict__ Zout, int d, int flags) {
  __shared__ short lds[24576];                  // 48 KB
  short* Af = lds;                              // [128 m][64 k]
  short* Ag = lds + 8192;
  short* Bt = lds + 16384;                      // [128 n][64 k]

  const int tid = threadIdx.x;
  const int wave = tid >> 6, lane = tid & 63;
  const int quad = lane >> 4, l16 = lane & 15;
  const int m0 = blockIdx.x * 128, t0 = blockIdx.y * 128, b = blockIdx.z;
  const int wm = wave >> 1, wn = wave & 1;

  f32x4 accf[4][4] = {};
  f32x4 accg[4][4] = {};

  for (int kk = 0; kk < 8; ++kk) {              // K = 512, BK = 64
    const int k0 = kk * 64;
    const int kw = kk >> 2;
    const int ci0 = k0 & 255;
    const int tshift = (kw == 0) ? -d : 0;      // tap 0 reads x[t-d]
    __syncthreads();                            // prev compute done
#pragma unroll
    for (int i = 0; i < 4; ++i) {
      int q = (i * 4 + wave) * 64 + lane;       // 0..1023 chunk id
      int r = q >> 3, kc = (q & 7) * 8;
      async16(Af + q * 8, Wf + (size_t)(m0 + r) * KTOT + k0 + kc);
      async16(Ag + q * 8, Wg + (size_t)(m0 + r) * KTOT + k0 + kc);
      async16(Bt + q * 8,
              Xin + ((size_t)(b * TPAD + PADT + t0 + r + tshift)) * NC + ci0 + kc);
    }
    __syncthreads();                            // drains vmcnt (async LDS loads)
#pragma unroll
    for (int ks = 0; ks < 2; ++ks) {
      s16x8 bfr[4];
#pragma unroll
      for (int ni = 0; ni < 4; ++ni)
        bfr[ni] = *(const s16x8*)&Bt[(wn * 64 + ni * 16 + l16) * 64 + ks * 32 + quad * 8];
#pragma unroll
      for (int mi = 0; mi < 4; ++mi) {
        s16x8 af = *(const s16x8*)&Af[(wm * 64 + mi * 16 + l16) * 64 + ks * 32 + quad * 8];
        s16x8 ag = *(const s16x8*)&Ag[(wm * 64 + mi * 16 + l16) * 64 + ks * 32 + quad * 8];
#pragma unroll
        for (int ni = 0; ni < 4; ++ni) {
          accf[mi][ni] = __builtin_amdgcn_mfma_f32_16x16x32_bf16(af, bfr[ni], accf[mi][ni], 0, 0, 0);
          accg[mi][ni] = __builtin_amdgcn_mfma_f32_16x16x32_bf16(ag, bfr[ni], accg[mi][ni], 0, 0, 0);
        }
      }
    }
  }
  __syncthreads();                              // all LDS reads done; reuse as ZT

  short* ZT = lds;                              // [128 t][128 c] bf16 (32 KB)
  const bool first = flags & 1;
  const bool last = flags & 2;

#pragma unroll
  for (int mi = 0; mi < 4; ++mi) {
#pragma unroll
    for (int ni = 0; ni < 4; ++ni) {
      const int mbase = m0 + wm * 64 + mi * 16 + quad * 4;   // global channel
      const int t = t0 + wn * 64 + ni * 16 + l16;            // global time
      short pk[4];
#pragma unroll
      for (int r = 0; r < 4; ++r) {
        float f = accf[mi][ni][r] + bia_f[mbase + r];
        float g = accg[mi][ni][r] + bia_g[mbase + r];
        float ef = __expf(2.f * f);
        float th = 1.f - 2.f / (ef + 1.f);      // tanh, no-overflow form
        float sg = 1.f / (1.f + __expf(-g));
        float z = th * sg;
        size_t zo = ((size_t)(b * NC + mbase + r)) * NT + t;
        if (first) Zout[zo] = z; else Zout[zo] += z;
        pk[r] = f2bf(z);
      }
      if (!last) {
        // C/D frag: 4 regs are 4 consecutive channels -> 8B LDS write
        short* dst = &ZT[(wn * 64 + ni * 16 + l16) * 128 + (wm * 64 + mi * 16 + quad * 4)];
        *(__attribute__((ext_vector_type(4))) short*)dst =
            (__attribute__((ext_vector_type(4))) short){pk[0], pk[1], pk[2], pk[3]};
      }
    }
  }
  if (!last) {
    __syncthreads();
#pragma unroll
    for (int i = 0; i < 8; ++i) {
      int q = tid + i * 256;                    // 2048 chunks of 16B
      int t = q >> 4, cc = (q & 15) * 8;
      s16x8 v = *(const s16x8*)&ZT[t * 128 + cc];
      *(s16x8*)&Xout[((size_t)(b * TPAD + PADT + t0 + t)) * NC + m0 + cc] = v;
    }
  }
}

// ---------------- launch ----------------
extern "C" void kernel_launch(void* const* d_in, const int* in_sizes, int n_in,
                              void* d_out, int out_size, void* d_ws, size_t ws_size,
                              hipStream_t stream) {
  const float* ys = (const float*)d_in[0];
  const float* fw = (const float*)d_in[1];
  const float* fb = (const float*)d_in[2];
  const float* gw = (const float*)d_in[3];
  const float* gb = (const float*)d_in[4];
  float* Zout = (float*)d_out;

  char* ws = (char*)d_ws;
  const size_t xbytes = (size_t)NB * TPAD * NC * 2;   // 34.6 MB each
  short* X0 = (short*)ws;
  short* X1 = (short*)(ws + xbytes);
  short* Wf = (short*)(ws + 2 * xbytes);
  short* Wg = Wf + (size_t)NLAYERS * NC * KTOT;

  hipLaunchKernelGGL(zero_pads, dim3(2048), dim3(256), 0, stream, X0, X1);
  hipLaunchKernelGGL(transpose_cast, dim3(64, 4, 16), dim3(256), 0, stream, ys, X0);
  hipLaunchKernelGGL(convert_w, dim3(4096), dim3(256), 0, stream, fw, gw, Wf, Wg);

  for (int l = 0; l < NLAYERS; ++l) {
    const short* Xin = (l & 1) ? X1 : X0;
    short* Xo = (l & 1) ? X0 : X1;
    int flags = (l == 0 ? 1 : 0) | (l == NLAYERS - 1 ? 2 : 0);
    hipLaunchKernelGGL(wavenet_layer, dim3(2, 32, 16), dim3(256), 0, stream,
                       Xin, Xo,
                       Wf + (size_t)l * NC * KTOT, Wg + (size_t)l * NC * KTOT,
                       fb + l * NC, gb + l * NC, Zout, 1 << l, flags);
  }
}

// Round 2
// 757.028 us; speedup vs baseline: 1.0361x; 1.0361x over previous
//
#include <hip/hip_runtime.h>

// WaveNet block: B=16, C=256, T=4096, LAYERS=8, K=2 (causal, dilation 2^l).
// bf16 MFMA GEMM per layer (M=256, N=B*T, K=512), 128x128 tile, BK=64,
// global_load_lds(16B) staging, XOR-swizzled LDS (kills 16-way conflicts).
// Zout deferred: layers write bf16 Zs chain; final kernel sums 8 Zs in fp32.

typedef __attribute__((ext_vector_type(8))) short s16x8;
typedef __attribute__((ext_vector_type(4))) short s16x4;
typedef __attribute__((ext_vector_type(4))) float f32x4;

#define NB 16
#define NC 256
#define NT 4096
#define TPAD 4224   // 128 (zero pad) + 4096
#define PADT 128
#define NLAYERS 8
#define KTOT 512    // C * Ktap

__device__ __forceinline__ short f2bf(float x) {
  union { float f; unsigned u; } v; v.f = x;
  unsigned u = v.u;
  unsigned r = (u + 0x7fffu + ((u >> 16) & 1u)) >> 16;  // RNE
  return (short)r;
}
__device__ __forceinline__ float bf2f(short s) {
  union { float f; unsigned u; } v; v.u = ((unsigned)(unsigned short)s) << 16;
  return v.f;
}

__device__ __forceinline__ void async16(short* lp, const short* gp) {
  __builtin_amdgcn_global_load_lds(
      (const __attribute__((address_space(1))) unsigned int*)gp,
      (__attribute__((address_space(3))) unsigned int*)lp,
      16, 0, 0);
}

// ---------------- prep kernels ----------------

// zero the t<0 pad region of nbuf consecutive X buffers (ws is poisoned 0xAA)
__global__ void zero_pads(short* __restrict__ base, int nbuf, size_t strideSh) {
  int idx = blockIdx.x * 256 + threadIdx.x;    // over nbuf * NB*PADT*NC
  if (idx >= nbuf * NB * PADT * NC) return;
  int j = idx >> 19;                            // / (NB*PADT*NC = 524288)
  int rem = idx & 524287;
  int b = rem >> 15;                            // / (PADT*NC)
  int r2 = rem & 32767;
  base[(size_t)j * strideSh + (size_t)b * TPAD * NC + r2] = 0;
}

// ys [b][c][t] fp32  ->  X0 [b][128+t][c] bf16 (LDS-tiled transpose)
__global__ void transpose_cast(const float* __restrict__ ys, short* __restrict__ X0) {
  __shared__ float tile[64][65];
  const int b = blockIdx.z, c0 = blockIdx.y * 64, t0 = blockIdx.x * 64;
  const int tid = threadIdx.x;
#pragma unroll
  for (int i = 0; i < 16; ++i) {
    int c = (tid >> 6) + i * 4;
    int t = tid & 63;
    tile[c][t] = ys[((size_t)(b * NC + c0 + c)) * NT + t0 + t];
  }
  __syncthreads();
#pragma unroll
  for (int i = 0; i < 2; ++i) {
    int q = tid + i * 256;                      // 512 chunks of 8 bf16
    int t = q >> 3, cc = (q & 7) * 8;
    s16x8 v;
#pragma unroll
    for (int j = 0; j < 8; ++j) v[j] = f2bf(tile[cc + j][t]);
    *(s16x8*)&X0[((size_t)(b * TPAD + PADT + t0 + t)) * NC + c0 + cc] = v;
  }
}

// weights [l][co][ci][kw] fp32 -> [l][co][kw*256+ci] bf16, filter & gate
__global__ void convert_w(const float* __restrict__ fw, const float* __restrict__ gw,
                          short* __restrict__ Wf, short* __restrict__ Wg) {
  int idx = blockIdx.x * 256 + threadIdx.x;     // over 8*256*512 = 1048576
  if (idx >= NLAYERS * NC * KTOT) return;
  int k = idx & (KTOT - 1);
  int row = idx >> 9;                           // l*256+co
  int kw = k >> 8, ci = k & 255;
  int src = (row * NC + ci) * 2 + kw;
  Wf[idx] = f2bf(fw[src]);
  Wg[idx] = f2bf(gw[src]);
}

// ---------------- fused layer kernel ----------------
// grid (2, 32, 16): m-tile, t-tile, batch.  256 threads = 4 waves.
// zmode: 0 = no Zout access (deferred), 1 = Zout store, 2 = Zout rmw.
// writeX: write bf16 Zs to Xout.
__global__ __launch_bounds__(256, 2)
void wavenet_layer(const short* __restrict__ Xin, short* __restrict__ Xout,
                   const short* __restrict__ Wf, const short* __restrict__ Wg,
                   const float* __restrict__ bia_f, const float* __restrict__ bia_g,
                   float* __restrict__ Zout, int d, int zmode, int writeX) {
  __shared__ short lds[24576];                  // 48 KB
  short* Af = lds;                              // [128 m][64 k], chunk-swizzled
  short* Ag = lds + 8192;
  short* Bt = lds + 16384;                      // [128 n][64 k], chunk-swizzled

  const int tid = threadIdx.x;
  const int wave = tid >> 6, lane = tid & 63;
  const int quad = lane >> 4, l16 = lane & 15;
  const int m0 = blockIdx.x * 128, t0 = blockIdx.y * 128, b = blockIdx.z;
  const int wm = wave >> 1, wn = wave & 1;
  const int xm = l16 & 7;                       // read-side XOR mask (row&7)

  f32x4 accf[4][4] = {};
  f32x4 accg[4][4] = {};

  for (int kk = 0; kk < 8; ++kk) {              // K = 512, BK = 64
    const int k0 = kk * 64;
    const int kw = kk >> 2;
    const int ci0 = k0 & 255;
    const int tshift = (kw == 0) ? -d : 0;      // tap 0 reads x[t-d]
    __syncthreads();                            // prev compute done
#pragma unroll
    for (int i = 0; i < 4; ++i) {
      int q = (i * 4 + wave) * 64 + lane;       // physical chunk id 0..1023
      int r = q >> 3;
      int kc = ((q & 7) ^ (r & 7)) * 8;         // swizzled source chunk
      async16(Af + q * 8, Wf + (size_t)(m0 + r) * KTOT + k0 + kc);
      async16(Ag + q * 8, Wg + (size_t)(m0 + r) * KTOT + k0 + kc);
      async16(Bt + q * 8,
              Xin + ((size_t)(b * TPAD + PADT + t0 + r + tshift)) * NC + ci0 + kc);
    }
    __syncthreads();                            // drains vmcnt (async LDS loads)
#pragma unroll
    for (int ks = 0; ks < 2; ++ks) {
      const int xo = ((ks * 4 + quad) ^ xm) * 8;  // swizzled chunk offset
      s16x8 bfr[4];
#pragma unroll
      for (int ni = 0; ni < 4; ++ni)
        bfr[ni] = *(const s16x8*)&Bt[(wn * 64 + ni * 16 + l16) * 64 + xo];
#pragma unroll
      for (int mi = 0; mi < 4; ++mi) {
        s16x8 af = *(const s16x8*)&Af[(wm * 64 + mi * 16 + l16) * 64 + xo];
        s16x8 ag = *(const s16x8*)&Ag[(wm * 64 + mi * 16 + l16) * 64 + xo];
#pragma unroll
        for (int ni = 0; ni < 4; ++ni) {
          accf[mi][ni] = __builtin_amdgcn_mfma_f32_16x16x32_bf16(af, bfr[ni], accf[mi][ni], 0, 0, 0);
          accg[mi][ni] = __builtin_amdgcn_mfma_f32_16x16x32_bf16(ag, bfr[ni], accg[mi][ni], 0, 0, 0);
        }
      }
    }
  }
  __syncthreads();                              // all LDS reads done; reuse as ZT

  short* ZT = lds;                              // [128 t][128 c] bf16, rotated

#pragma unroll
  for (int mi = 0; mi < 4; ++mi) {
#pragma unroll
    for (int ni = 0; ni < 4; ++ni) {
      const int mbase = m0 + wm * 64 + mi * 16 + quad * 4;   // global channel
      const int tl = wn * 64 + ni * 16 + l16;                // tile-local time
      const int t = t0 + tl;                                 // global time
      short pk[4];
#pragma unroll
      for (int r = 0; r < 4; ++r) {
        float f = accf[mi][ni][r] + bia_f[mbase + r];
        float g = accg[mi][ni][r] + bia_g[mbase + r];
        float ef = __expf(2.f * f);
        float th = 1.f - 2.f / (ef + 1.f);      // tanh, no-overflow form
        float sg = 1.f / (1.f + __expf(-g));
        float z = th * sg;
        if (zmode) {
          size_t zo = ((size_t)(b * NC + mbase + r)) * NT + t;
          if (zmode == 1) Zout[zo] = z; else Zout[zo] += z;
        }
        pk[r] = f2bf(z);
      }
      if (writeX) {
        // rotate-swizzle: physical col = (c + t*8) & 127  (stays 4-aligned)
        int cloc = wm * 64 + mi * 16 + quad * 4;
        short* dst = &ZT[tl * 128 + ((cloc + tl * 8) & 127)];
        *(s16x4*)dst = (s16x4){pk[0], pk[1], pk[2], pk[3]};
      }
    }
  }
  if (writeX) {
    __syncthreads();
#pragma unroll
    for (int i = 0; i < 8; ++i) {
      int q = tid + i * 256;                    // 2048 chunks of 16B
      int t = q >> 4, cc = (q & 15) * 8;
      s16x8 v = *(const s16x8*)&ZT[t * 128 + ((cc + t * 8) & 127)];
      *(s16x8*)&Xout[((size_t)(b * TPAD + PADT + t0 + t)) * NC + m0 + cc] = v;
    }
  }
}

// ---------------- final sum + transpose ----------------
// Zout[b][c][t] fp32 = sum over l=1..8 of buf_l[b][128+t][c] (bf16)
__global__ void sum_transpose(const short* __restrict__ base, size_t strideSh,
                              float* __restrict__ Zout) {
  __shared__ float tile[64][65];
  const int b = blockIdx.z, c0 = blockIdx.y * 64, t0 = blockIdx.x * 64;
  const int tid = threadIdx.x;
  float acc[2][8] = {};
#pragma unroll
  for (int l = 1; l <= NLAYERS; ++l) {
    const short* buf = base + (size_t)l * strideSh;
#pragma unroll
    for (int j = 0; j < 2; ++j) {
      int chunk = tid + j * 256;                // 512 chunks of 8 bf16
      int tl = chunk >> 3, cc = (chunk & 7) * 8;
      s16x8 v = *(const s16x8*)&buf[((size_t)(b * TPAD + PADT + t0 + tl)) * NC + c0 + cc];
#pragma unroll
      for (int e = 0; e < 8; ++e) acc[j][e] += bf2f(v[e]);
    }
  }
#pragma unroll
  for (int j = 0; j < 2; ++j) {
    int chunk = tid + j * 256;
    int tl = chunk >> 3, cc = (chunk & 7) * 8;
#pragma unroll
    for (int e = 0; e < 8; ++e) tile[tl][cc + e] = acc[j][e];
  }
  __syncthreads();
#pragma unroll
  for (int i = 0; i < 4; ++i) {
    int c = (tid >> 4) + i * 16;
    int t = (tid & 15) * 4;
    float4 v = make_float4(tile[t][c], tile[t + 1][c], tile[t + 2][c], tile[t + 3][c]);
    *(float4*)&Zout[((size_t)(b * NC + c0 + c)) * NT + t0 + t] = v;
  }
}

// ---------------- launch ----------------
extern "C" void kernel_launch(void* const* d_in, const int* in_sizes, int n_in,
                              void* d_out, int out_size, void* d_ws, size_t ws_size,
                              hipStream_t stream) {
  const float* ys = (const float*)d_in[0];
  const float* fw = (const float*)d_in[1];
  const float* fb = (const float*)d_in[2];
  const float* gw = (const float*)d_in[3];
  const float* gb = (const float*)d_in[4];
  float* Zout = (float*)d_out;

  char* ws = (char*)d_ws;
  const size_t xbytes = (size_t)NB * TPAD * NC * 2;      // 34.6 MB each
  const size_t strideSh = xbytes / 2;
  const size_t wcount = (size_t)NLAYERS * NC * KTOT;     // per tensor
  const size_t need = 9 * xbytes + 2 * wcount * 2;

  const bool deferred = (ws_size >= need);

  short* Xbase = (short*)ws;
  short* Wf;
  if (deferred) Wf = (short*)(ws + 9 * xbytes);
  else          Wf = (short*)(ws + 2 * xbytes);
  short* Wg = Wf + wcount;

  {
    int nbuf = deferred ? 8 : 2;
    int total = nbuf * NB * PADT * NC;
    hipLaunchKernelGGL(zero_pads, dim3((total + 255) / 256), dim3(256), 0, stream,
                       Xbase, nbuf, strideSh);
  }
  hipLaunchKernelGGL(transpose_cast, dim3(64, 4, 16), dim3(256), 0, stream, ys, Xbase);
  hipLaunchKernelGGL(convert_w, dim3(4096), dim3(256), 0, stream, fw, gw, Wf, Wg);

  for (int l = 0; l < NLAYERS; ++l) {
    const short* Xin;
    short* Xo;
    int zmode, writeX;
    if (deferred) {
      Xin = Xbase + (size_t)l * strideSh;
      Xo = Xbase + (size_t)(l + 1) * strideSh;
      zmode = 0;
      writeX = 1;
    } else {
      Xin = (l & 1) ? Xbase + strideSh : Xbase;
      Xo = (l & 1) ? Xbase : Xbase + strideSh;
      zmode = (l == 0) ? 1 : 2;
      writeX = (l < NLAYERS - 1) ? 1 : 0;
    }
    hipLaunchKernelGGL(wavenet_layer, dim3(2, 32, 16), dim3(256), 0, stream,
                       Xin, Xo,
                       Wf + (size_t)l * NC * KTOT, Wg + (size_t)l * NC * KTOT,
                       fb + l * NC, gb + l * NC, Zout, 1 << l, zmode, writeX);
  }
  if (deferred) {
    hipLaunchKernelGGL(sum_transpose, dim3(64, 4, 16), dim3(256), 0, stream,
                       Xbase, strideSh, Zout);
  }
}